// Round 1
// baseline (450.162 us; speedup 1.0000x reference)
//
#include <hip/hip_runtime.h>
#include <math.h>

#define EPS 1e-5f
constexpr int D = 64;

// ---------------- K2: scatter-add, one wave (64 lanes) per edge ----------------
__global__ void scatter_kernel(const float* __restrict__ x,
                               const int* __restrict__ ei,
                               float* __restrict__ sums,
                               float* __restrict__ cntf,
                               int E, int N) {
    long long gid = (long long)blockIdx.x * blockDim.x + threadIdx.x;
    int e = (int)(gid >> 6);
    int d = (int)(gid & 63);
    if (e >= E) return;
    int src = ei[e];
    int dst = ei[E + e];
    // clamp (insurance against dtype surprises -> avoid OOB crash)
    src = min(max(src, 0), N - 1);
    dst = min(max(dst, 0), N - 1);
    atomicAdd(&sums[(long long)dst * D + d], x[(long long)src * D + d]);
    if (d == 0) atomicAdd(&cntf[dst], 1.0f);
}

// ------- K3: out = (sums/max(cnt,1)) @ Wl^T + b + x @ Wr^T, + global stats -----
// One wave per row. Lane j owns output column j and holds Wl[j][:], Wr[j][:]
// in 128 VGPRs. Row data broadcast via v_readlane (unrolled, const lane idx).
__global__ __launch_bounds__(256) void fused_linear_kernel(
        const float* __restrict__ x, const float* __restrict__ sums,
        const float* __restrict__ cntf, const float* __restrict__ Wl,
        const float* __restrict__ bl, const float* __restrict__ Wr,
        float* __restrict__ out, float* stats, int N) {
    const int lane = threadIdx.x & 63;
    const int wid = blockIdx.x * (blockDim.x >> 6) + (threadIdx.x >> 6);
    const int nwaves = gridDim.x * (blockDim.x >> 6);

    float wl[D], wr[D];
#pragma unroll
    for (int d4 = 0; d4 < D / 4; ++d4) {
        float4 a = *(const float4*)&Wl[lane * D + d4 * 4];
        float4 b = *(const float4*)&Wr[lane * D + d4 * 4];
        wl[d4 * 4 + 0] = a.x; wl[d4 * 4 + 1] = a.y;
        wl[d4 * 4 + 2] = a.z; wl[d4 * 4 + 3] = a.w;
        wr[d4 * 4 + 0] = b.x; wr[d4 * 4 + 1] = b.y;
        wr[d4 * 4 + 2] = b.z; wr[d4 * 4 + 3] = b.w;
    }
    const float bj = bl[lane];

    float ls = 0.0f, lsq = 0.0f;
    for (int n = wid; n < N; n += nwaves) {
        float sj = sums[(long long)n * D + lane];
        float xj = x[(long long)n * D + lane];
        float c = cntf[n];
        float inv_c = 1.0f / fmaxf(c, 1.0f);
        float accl = 0.0f, accr = 0.0f;
#pragma unroll
        for (int d = 0; d < D; ++d) {
            float sd = __uint_as_float(
                __builtin_amdgcn_readlane(__float_as_uint(sj), d));
            float xd = __uint_as_float(
                __builtin_amdgcn_readlane(__float_as_uint(xj), d));
            accl = fmaf(sd, wl[d], accl);
            accr = fmaf(xd, wr[d], accr);
        }
        float v = accl * inv_c + accr + bj;
        out[(long long)n * D + lane] = v;
        ls += v;
        lsq += v * v;
    }
    // wave-level reduction (64 lanes)
    for (int off = 32; off > 0; off >>= 1) {
        ls += __shfl_down(ls, off, 64);
        lsq += __shfl_down(lsq, off, 64);
    }
    if (lane == 0) {
        atomicAdd(&stats[0], ls);
        atomicAdd(&stats[1], lsq);
    }
}

// ---------------- K4: in-place graph layernorm on d_out ----------------
__global__ void norm_kernel(const float* __restrict__ stats,
                            const float* __restrict__ lw,
                            const float* __restrict__ lb,
                            float* out, long long M4) {
    long long i = (long long)blockIdx.x * blockDim.x + threadIdx.x;
    if (i >= M4) return;
    const float inv_M = 1.0f / (float)(M4 * 4);
    float mu = stats[0] * inv_M;
    float var = stats[1] * inv_M - mu * mu;
    float rs = 1.0f / sqrtf(var + EPS);
    float4 v = ((const float4*)out)[i];
    int col = (int)((i * 4) & (D - 1));
    float4 w = *(const float4*)&lw[col];
    float4 b = *(const float4*)&lb[col];
    v.x = (v.x - mu) * rs * w.x + b.x;
    v.y = (v.y - mu) * rs * w.y + b.y;
    v.z = (v.z - mu) * rs * w.z + b.z;
    v.w = (v.w - mu) * rs * w.w + b.w;
    ((float4*)out)[i] = v;
}

extern "C" void kernel_launch(void* const* d_in, const int* in_sizes, int n_in,
                              void* d_out, int out_size, void* d_ws, size_t ws_size,
                              hipStream_t stream) {
    const float* x  = (const float*)d_in[0];
    const int*   ei = (const int*)d_in[1];
    const float* Wl = (const float*)d_in[2];
    const float* bl = (const float*)d_in[3];
    const float* Wr = (const float*)d_in[4];
    const float* lw = (const float*)d_in[5];
    const float* lb = (const float*)d_in[6];
    float* out = (float*)d_out;

    const int N = in_sizes[0] / D;       // 100000
    const int E = in_sizes[1] / 2;       // 1200000

    float* sums  = (float*)d_ws;                    // N*D floats
    float* cntf  = sums + (size_t)N * D;            // N floats
    float* stats = cntf + N;                        // 2 floats

    size_t zero_bytes = ((size_t)N * D + N + 2) * sizeof(float);
    hipMemsetAsync(d_ws, 0, zero_bytes, stream);

    long long t2 = (long long)E * 64;
    int blocks2 = (int)((t2 + 255) / 256);
    scatter_kernel<<<blocks2, 256, 0, stream>>>(x, ei, sums, cntf, E, N);

    fused_linear_kernel<<<640, 256, 0, stream>>>(x, sums, cntf, Wl, bl, Wr,
                                                 out, stats, N);

    long long M4 = (long long)N * D / 4;
    int blocks4 = (int)((M4 + 255) / 256);
    norm_kernel<<<blocks4, 256, 0, stream>>>(stats, lw, lb, out, M4);
}